// Round 4
// baseline (1539.650 us; speedup 1.0000x reference)
//
#include <hip/hip_runtime.h>

// Problem sizes
// B=8 M=4 T=2048 E=768 P=256 K=64 V=64 H=128 NEXP=16 COMB=384 HID=192
// tokens NT = 65536, sequences NSEQ = 32

typedef unsigned short u16;
typedef float f32x4 __attribute__((ext_vector_type(4)));
typedef short s16x8 __attribute__((ext_vector_type(8)));
typedef unsigned u32x2 __attribute__((ext_vector_type(2)));

#define DI static __device__ __forceinline__

DI u16 f2b(float f) {  // fp32 -> bf16 RNE
  unsigned u = __builtin_bit_cast(unsigned, f);
  u += 0x7fffu + ((u >> 16) & 1u);
  return (u16)(u >> 16);
}
DI float b2f(u16 s) { return __builtin_bit_cast(float, ((unsigned)s) << 16); }
DI float rcp_fast(float x) { return __builtin_amdgcn_rcpf(x); }
DI f32x4 mfma16(s16x8 a, s16x8 b, f32x4 c) {
  return __builtin_amdgcn_mfma_f32_16x16x32_bf16(a, b, c, 0, 0, 0);
}

// ---- workspace layout (bytes) ----
#define OFF_COMB   0ull            // u16 [65536][384]  (proc | rus)      50331648
#define OFF_URS    50331648ull     // f32 [32][2048][4] {U, rbar, sbar, 0} 1048576
#define OFF_TPWB   51380736ull     // u16 [256][768]                        393216
#define OFF_WHHB   51773952ull     // u16 [384][128]  (unused by gru now)    98304
#define OFF_W1B    51872256ull     // u16 [192][384]                        147456
#define OFF_W2B    52019712ull     // u16 [16][192]                           6144
#define OFF_WABC   52025856ull     // f32 wA[256] wB[256] wC[256]             3072
#define OFF_CABC   52028928ull     // f32 cA cB cC pad                          16
#define OFF_GX     52028944ull     // f32 gxu[384] gxr[384] gxs[384] gxc[384] 6144

// =====================================================================
// K0: derived weights + bf16 conversions
// =====================================================================
__global__ __launch_bounds__(512) void k_prep(
    const float* __restrict__ qw, const float* __restrict__ qb,
    const float* __restrict__ kw, const float* __restrict__ kb,
    const float* __restrict__ vw, const float* __restrict__ vb,
    const float* __restrict__ wih, const float* __restrict__ bih,
    const float* __restrict__ tpw,
    const float* __restrict__ w1, const float* __restrict__ w2,
    u16* __restrict__ tpwb,
    u16* __restrict__ w1b, u16* __restrict__ w2b,
    float* __restrict__ wabc, float* __restrict__ cabc, float* __restrict__ gx) {
  const int tid = threadIdx.x, bid = blockIdx.x;
  if (bid == 0 && tid < 256) {
    int p = tid;
    float a = 0.f, b = 0.f, c = 0.f;
    for (int j = 0; j < 64; j++) {
      float q = qw[j * 256 + p];
      a += q * kw[2 * j]; b += q * kw[2 * j + 1]; c += q * kb[j];
    }
    wabc[p] = a; wabc[256 + p] = b; wabc[512 + p] = c;
    if (p == 0) {
      float ca = 0.f, cb = 0.f, cc = 0.f;
      for (int j = 0; j < 64; j++) {
        ca += qb[j] * kw[2 * j]; cb += qb[j] * kw[2 * j + 1]; cc += qb[j] * kb[j];
      }
      cabc[0] = ca; cabc[1] = cb; cabc[2] = cc; cabc[3] = 0.f;
    }
  }
  if (bid == 1 && tid < 384) {
    int j = tid;
    float r = 0.f, s = 0.f, c0 = 0.f;
    for (int v = 0; v < 64; v++) {
      float w = wih[j * 65 + 1 + v];
      r += w * vw[2 * v]; s += w * vw[2 * v + 1]; c0 += w * vb[v];
    }
    gx[j] = wih[j * 65]; gx[384 + j] = r; gx[768 + j] = s; gx[1152 + j] = c0 + bih[j];
  }
  const int n1 = 768 * 256, n3 = 192 * 384, n4 = 16 * 192;
  const int total = n1 + n3 + n4;
  for (int i = bid * blockDim.x + tid; i < total; i += gridDim.x * blockDim.x) {
    if (i < n1) tpwb[i] = f2b(tpw[i]);
    else if (i < n1 + n3) w1b[i - n1] = f2b(w1[i - n1]);
    else w2b[i - n1 - n3] = f2b(w2[i - n1 - n3]);
  }
}

// =====================================================================
// K1: processed = relu(TE @ tp_w.T + tp_b)  -> comb[:, 0:256] (bf16)
// 128x256 tile per block, BK=64, bf16 MFMA, XOR-swizzled LDS
// =====================================================================
__global__ __launch_bounds__(512, 1) void k_gemm1(
    const float* __restrict__ te, const float* __restrict__ tpb,
    const u16* __restrict__ tpwb, u16* __restrict__ comb) {
  __shared__ u16 Als[128 * 64];
  __shared__ u16 Bls[256 * 64];
  const int tid = threadIdx.x;
  const int lane = tid & 63, w = tid >> 6;
  const int c = lane & 15, g4 = lane >> 4;
  const int wm = w >> 2, wn = w & 3;
  const long row0 = (long)blockIdx.x * 128;

  f32x4 acc[4][4];
  #pragma unroll
  for (int i = 0; i < 4; i++)
    #pragma unroll
    for (int j = 0; j < 4; j++) acc[i][j] = (f32x4)(0.f);

  for (int kk = 0; kk < 12; kk++) {
    // stage A (fp32 -> bf16 inline)
    #pragma unroll
    for (int ii = 0; ii < 2; ii++) {
      int idx = tid + 512 * ii;
      int row = idx >> 3, kb = idx & 7;
      const float* g = te + (row0 + row) * 768 + kk * 64 + kb * 8;
      f32x4 p0 = *(const f32x4*)g;
      f32x4 p1 = *(const f32x4*)(g + 4);
      s16x8 v;
      v[0] = f2b(p0[0]); v[1] = f2b(p0[1]); v[2] = f2b(p0[2]); v[3] = f2b(p0[3]);
      v[4] = f2b(p1[0]); v[5] = f2b(p1[1]); v[6] = f2b(p1[2]); v[7] = f2b(p1[3]);
      *(s16x8*)&Als[row * 64 + ((kb ^ (row & 7)) << 3)] = v;
    }
    // stage B
    #pragma unroll
    for (int ii = 0; ii < 4; ii++) {
      int idx = tid + 512 * ii;
      int n = idx >> 3, kb = idx & 7;
      s16x8 v = *(const s16x8*)(tpwb + n * 768 + kk * 64 + kb * 8);
      *(s16x8*)&Bls[n * 64 + ((kb ^ (n & 7)) << 3)] = v;
    }
    __syncthreads();
    #pragma unroll
    for (int kt = 0; kt < 2; kt++) {
      s16x8 af[4], bf[4];
      #pragma unroll
      for (int mt = 0; mt < 4; mt++) {
        int row = wm * 64 + mt * 16 + c;
        af[mt] = *(const s16x8*)&Als[row * 64 + (((kt * 4 + g4) ^ (row & 7)) << 3)];
      }
      #pragma unroll
      for (int nt = 0; nt < 4; nt++) {
        int n = wn * 64 + nt * 16 + c;
        bf[nt] = *(const s16x8*)&Bls[n * 64 + (((kt * 4 + g4) ^ (n & 7)) << 3)];
      }
      #pragma unroll
      for (int mt = 0; mt < 4; mt++)
        #pragma unroll
        for (int nt = 0; nt < 4; nt++)
          acc[mt][nt] = mfma16(af[mt], bf[nt], acc[mt][nt]);
    }
    __syncthreads();
  }
  #pragma unroll
  for (int nt = 0; nt < 4; nt++) {
    int col = wn * 64 + nt * 16 + c;
    float bias = tpb[col];
    #pragma unroll
    for (int mt = 0; mt < 4; mt++)
      #pragma unroll
      for (int r = 0; r < 4; r++) {
        long row = row0 + wm * 64 + mt * 16 + g4 * 4 + r;
        float v = fmaxf(acc[mt][nt][r] + bias, 0.f);
        comb[row * 384 + col] = f2b(v);
      }
  }
}

// =====================================================================
// K2: collapsed attention. Per token: 3 dots of 256, softmax over 3
// "others", emit (U, rbar, sbar). One wave per token.
// urs layout: [seq][t][4] (seq-major so k_gru can bulk-load its slice)
// =====================================================================
__global__ __launch_bounds__(256) void k_attn(
    const u16* __restrict__ comb, const float* __restrict__ U,
    const float* __restrict__ R, const float* __restrict__ S,
    const float* __restrict__ wabc, const float* __restrict__ cabc,
    float* __restrict__ urs) {
  const int lane = threadIdx.x & 63;
  const long token = (long)blockIdx.x * 4 + (threadIdx.x >> 6);
  const int t = (int)(token & 2047);
  const int seq = (int)(token >> 11);
  const int m = seq & 3;

  u32x2 pv = *(const u32x2*)(comb + token * 384 + lane * 4);
  float p0 = __builtin_bit_cast(float, pv[0] << 16);
  float p1 = __builtin_bit_cast(float, pv[0] & 0xffff0000u);
  float p2 = __builtin_bit_cast(float, pv[1] << 16);
  float p3 = __builtin_bit_cast(float, pv[1] & 0xffff0000u);
  f32x4 wa = *(const f32x4*)(wabc + lane * 4);
  f32x4 wb = *(const f32x4*)(wabc + 256 + lane * 4);
  f32x4 wc = *(const f32x4*)(wabc + 512 + lane * 4);
  float a = p0 * wa[0] + p1 * wa[1] + p2 * wa[2] + p3 * wa[3];
  float b = p0 * wb[0] + p1 * wb[1] + p2 * wb[2] + p3 * wb[3];
  float cd = p0 * wc[0] + p1 * wc[1] + p2 * wc[2] + p3 * wc[3];
  #pragma unroll
  for (int off = 32; off; off >>= 1) {
    a += __shfl_xor(a, off); b += __shfl_xor(b, off); cd += __shfl_xor(cd, off);
  }
  a += cabc[0]; b += cabc[1]; cd += cabc[2];

  float rv[3], sv[3], sc[3];
  #pragma unroll
  for (int n = 0; n < 3; n++) {
    int o = n + (n >= m ? 1 : 0);
    long idx = ((long)seq * 4 + o) * 2048 + t;
    rv[n] = R[idx]; sv[n] = S[idx];
    sc[n] = (a * rv[n] + b * sv[n] + cd) * 0.125f;
  }
  float mx = fmaxf(sc[0], fmaxf(sc[1], sc[2]));
  float e0 = __expf(sc[0] - mx), e1 = __expf(sc[1] - mx), e2 = __expf(sc[2] - mx);
  float inv = rcp_fast(e0 + e1 + e2);
  float rb = (e0 * rv[0] + e1 * rv[1] + e2 * rv[2]) * inv;
  float sb = (e0 * sv[0] + e1 * sv[1] + e2 * sv[2]) * inv;
  if (lane == 0) {
    f32x4 v; v[0] = U[token]; v[1] = rb; v[2] = sb; v[3] = 0.f;
    *(f32x4*)(urs + ((long)seq * 2048 + t) * 4) = v;
  }
}

// =====================================================================
// K3: GRU scan — VALU matvec (no MFMA; old path did 16x redundant work
// on the matrix pipe: 466 cyc/step issue vs 192 here).
// 1 block/seq, 256 threads. Thread t: col c=t>>1 (ALL 3 gates -> the
// n-gate's r-dependence stays in-thread), k-half kh=t&1. w_hh rows
// {c,128+c,256+c} fp32-resident in 192 VGPRs. h fp32 in LDS (dbuf);
// k-half partials combined with one in-wave shfl_xor(1).
// No global memory ops in the step loop (urs preloaded, hist chunks
// flushed every 32 steps).
// =====================================================================
__global__ __launch_bounds__(256, 1) void k_gru(
    const float* __restrict__ whh, const float* __restrict__ bhh,
    const float* __restrict__ gx, const float* __restrict__ urs,
    u16* __restrict__ comb) {
  __shared__ float hbuf[2][128];      // fp32 h, double-buffered
  __shared__ u16 hist[2][32][128];    // 16 KB history chunks (bf16)
  __shared__ float ulds[2048][4];     // 32 KB urs slice for this seq
  const int tid = threadIdx.x;
  const int c = tid >> 1, kh = tid & 1;
  const int seq = blockIdx.x;

  // one-time bulk load of this sequence's urs slice (contiguous 32 KB)
  for (int i = tid; i < 2048; i += 256)
    *(f32x4*)&ulds[i][0] = *(const f32x4*)(urs + ((long)seq * 2048 + i) * 4);

  // resident weights: rows c (r), 128+c (z), 256+c (n); k in [kh*64, kh*64+64)
  f32x4 wr[16], wz[16], wn[16];
  {
    const float* pr = whh + (long)c * 128 + kh * 64;
    const float* pz = whh + (long)(128 + c) * 128 + kh * 64;
    const float* pn = whh + (long)(256 + c) * 128 + kh * 64;
    #pragma unroll
    for (int i = 0; i < 16; i++) {
      wr[i] = *(const f32x4*)(pr + 4 * i);
      wz[i] = *(const f32x4*)(pz + 4 * i);
      wn[i] = *(const f32x4*)(pn + 4 * i);
    }
  }
  const float gu_r = gx[c],       grr = gx[384 + c],   gs_r = gx[768 + c],   gc_r = gx[1152 + c];
  const float gu_z = gx[128 + c], grz = gx[512 + c],   gs_z = gx[896 + c],   gc_z = gx[1280 + c];
  const float gu_n = gx[256 + c], grn = gx[640 + c],   gs_n = gx[1024 + c],  gc_n = gx[1408 + c];
  const float bh_r = bhh[c], bh_z = bhh[128 + c], bh_n = bhh[256 + c];

  if (tid < 128) { hbuf[0][tid] = 0.f; hbuf[1][tid] = 0.f; }
  float hp = 0.f;
  __syncthreads();  // also drains the urs preload

  u16* rbase = comb + (long)seq * 2048 * 384 + 256;
  for (int chunk = 0; chunk < 64; chunk++) {
    #pragma unroll 1
    for (int s = 0; s < 32; s++) {
      const int t = chunk * 32 + s;
      f32x4 uc = *(const f32x4*)&ulds[t][0];   // broadcast, no vmem
      const float* hb = &hbuf[t & 1][kh * 64];
      f32x4 ar = (f32x4)(0.f), az = (f32x4)(0.f), an = (f32x4)(0.f);
      #pragma unroll
      for (int i = 0; i < 16; i++) {
        f32x4 hv = *(const f32x4*)(hb + 4 * i);   // 2-addr broadcast (free)
        ar += hv * wr[i]; az += hv * wz[i]; an += hv * wn[i];
      }
      float hr = (ar[0] + ar[1]) + (ar[2] + ar[3]);
      float hz = (az[0] + az[1]) + (az[2] + az[3]);
      float hn = (an[0] + an[1]) + (an[2] + an[3]);
      hr += __shfl_xor(hr, 1);  // combine k-halves (partner = adjacent lane)
      hz += __shfl_xor(hz, 1);
      hn += __shfl_xor(hn, 1);
      hr += bh_r; hz += bh_z; hn += bh_n;
      const float uu = uc[0], rbv = uc[1], sbv = uc[2];
      const float xr = gc_r + uu * gu_r + rbv * grr + sbv * gs_r;
      const float xz = gc_z + uu * gu_z + rbv * grz + sbv * gs_z;
      const float xn = gc_n + uu * gu_n + rbv * grn + sbv * gs_n;
      const float r = rcp_fast(1.f + __expf(-(xr + hr)));
      const float z = rcp_fast(1.f + __expf(-(xz + hz)));
      const float e = __expf(2.f * (xn + r * hn));
      const float n = 1.f - 2.f * rcp_fast(e + 1.f);
      const float h = z * (hp - n) + n;
      hp = h;
      if (kh == 0) {
        hbuf[(t + 1) & 1][c] = h;
        hist[chunk & 1][s][c] = f2b(h);
      }
      __syncthreads();
    }
    // flush chunk history: 32 rows x 256 B, coalesced 16 B stores,
    // fire-and-forget (drained at the next step's barrier, amortized /32)
    const int t0 = chunk * 32;
    #pragma unroll
    for (int ii = 0; ii < 2; ii++) {
      int idx = tid + 256 * ii;
      int row = idx >> 4, part = idx & 15;
      s16x8 v = *(const s16x8*)&hist[chunk & 1][row][part * 8];
      *(s16x8*)(rbase + (long)(t0 + row) * 384 + part * 8) = v;
    }
  }
}

// =====================================================================
// K4: fused MLP: hid = relu(comb @ w1.T + b1) (bf16 via LDS), then
// logits = hid @ w2.T + b2 (fp32 out). 128 rows per block.
// =====================================================================
__global__ __launch_bounds__(512, 1) void k_mlp(
    const u16* __restrict__ comb, const u16* __restrict__ w1b,
    const float* __restrict__ b1, const u16* __restrict__ w2b,
    const float* __restrict__ b2, float* __restrict__ out) {
  __shared__ u16 smem[40960];  // 80 KB
  u16* Als = smem;             // 128x128
  u16* Bls = smem + 16384;     // 192x128
  u16* Hls = smem;             // 128x192 (reuse after barrier)
  const int tid = threadIdx.x;
  const int lane = tid & 63, w = tid >> 6;
  const int c = lane & 15, g4 = lane >> 4;
  const int wm = w >> 2, wn = w & 3;
  const long row0 = (long)blockIdx.x * 128;

  s16x8 w2f[6];
  #pragma unroll
  for (int kt = 0; kt < 6; kt++)
    w2f[kt] = *(const s16x8*)(w2b + c * 192 + kt * 32 + g4 * 8);
  const float b2v = b2[c];

  f32x4 acc[4][3];
  #pragma unroll
  for (int i = 0; i < 4; i++)
    #pragma unroll
    for (int j = 0; j < 3; j++) acc[i][j] = (f32x4)(0.f);

  for (int kc = 0; kc < 3; kc++) {
    #pragma unroll
    for (int ii = 0; ii < 4; ii++) {
      int idx = tid + 512 * ii;
      int row = idx >> 4, kb = idx & 15;
      s16x8 v = *(const s16x8*)(comb + (row0 + row) * 384 + kc * 128 + kb * 8);
      *(s16x8*)&Als[row * 128 + ((kb ^ (row & 7)) << 3)] = v;
    }
    #pragma unroll
    for (int ii = 0; ii < 6; ii++) {
      int idx = tid + 512 * ii;
      int n = idx >> 4, kb = idx & 15;
      s16x8 v = *(const s16x8*)(w1b + n * 384 + kc * 128 + kb * 8);
      *(s16x8*)&Bls[n * 128 + ((kb ^ (n & 7)) << 3)] = v;
    }
    __syncthreads();
    #pragma unroll
    for (int kt = 0; kt < 4; kt++) {
      s16x8 af[4], bf[3];
      #pragma unroll
      for (int mt = 0; mt < 4; mt++) {
        int row = wm * 64 + mt * 16 + c;
        af[mt] = *(const s16x8*)&Als[row * 128 + (((kt * 4 + g4) ^ (row & 7)) << 3)];
      }
      #pragma unroll
      for (int nt = 0; nt < 3; nt++) {
        int n = wn * 48 + nt * 16 + c;
        bf[nt] = *(const s16x8*)&Bls[n * 128 + (((kt * 4 + g4) ^ (n & 7)) << 3)];
      }
      #pragma unroll
      for (int mt = 0; mt < 4; mt++)
        #pragma unroll
        for (int nt = 0; nt < 3; nt++)
          acc[mt][nt] = mfma16(af[mt], bf[nt], acc[mt][nt]);
    }
    __syncthreads();
  }
  // hid -> LDS (bf16, swizzled)
  #pragma unroll
  for (int nt = 0; nt < 3; nt++) {
    int col = wn * 48 + nt * 16 + c;
    float bias = b1[col];
    int cb = col >> 3, cl = col & 7;
    #pragma unroll
    for (int mt = 0; mt < 4; mt++)
      #pragma unroll
      for (int r = 0; r < 4; r++) {
        int row = wm * 64 + mt * 16 + g4 * 4 + r;
        float v = fmaxf(acc[mt][nt][r] + bias, 0.f);
        Hls[row * 192 + ((cb ^ (row & 7)) << 3) + cl] = f2b(v);
      }
  }
  __syncthreads();
  // gemm2: 16 outputs, K=192
  f32x4 a2 = (f32x4)(0.f);
  const int row = w * 16 + c, r7 = row & 7;
  #pragma unroll
  for (int kt = 0; kt < 6; kt++) {
    s16x8 af = *(const s16x8*)&Hls[row * 192 + (((kt * 4 + g4) ^ r7) << 3)];
    a2 = mfma16(af, w2f[kt], a2);
  }
  #pragma unroll
  for (int r = 0; r < 4; r++) {
    long grow = row0 + w * 16 + g4 * 4 + r;
    out[grow * 16 + c] = a2[r] + b2v;
  }
}

// =====================================================================
extern "C" void kernel_launch(void* const* d_in, const int* in_sizes, int n_in,
                              void* d_out, int out_size, void* d_ws, size_t ws_size,
                              hipStream_t stream) {
  (void)in_sizes; (void)n_in; (void)out_size; (void)ws_size;
  const float* te  = (const float*)d_in[0];
  const float* U   = (const float*)d_in[1];
  const float* R   = (const float*)d_in[2];
  const float* S   = (const float*)d_in[3];
  const float* tpw = (const float*)d_in[4];
  const float* tpb = (const float*)d_in[5];
  const float* qw  = (const float*)d_in[6];
  const float* qb  = (const float*)d_in[7];
  const float* kw  = (const float*)d_in[8];
  const float* kb  = (const float*)d_in[9];
  const float* vw  = (const float*)d_in[10];
  const float* vb  = (const float*)d_in[11];
  const float* wih = (const float*)d_in[12];
  const float* whh = (const float*)d_in[13];
  const float* bih = (const float*)d_in[14];
  const float* bhh = (const float*)d_in[15];
  const float* w1  = (const float*)d_in[16];
  const float* b1  = (const float*)d_in[17];
  const float* w2  = (const float*)d_in[18];
  const float* b2  = (const float*)d_in[19];

  char* ws = (char*)d_ws;
  u16*   comb = (u16*)(ws + OFF_COMB);
  float* urs  = (float*)(ws + OFF_URS);
  u16*   tpwb = (u16*)(ws + OFF_TPWB);
  u16*   w1b  = (u16*)(ws + OFF_W1B);
  u16*   w2b  = (u16*)(ws + OFF_W2B);
  float* wabc = (float*)(ws + OFF_WABC);
  float* cabc = (float*)(ws + OFF_CABC);
  float* gx   = (float*)(ws + OFF_GX);
  float* out  = (float*)d_out;

  hipLaunchKernelGGL(k_prep, dim3(32), dim3(512), 0, stream,
                     qw, qb, kw, kb, vw, vb, wih, bih, tpw, w1, w2,
                     tpwb, w1b, w2b, wabc, cabc, gx);
  hipLaunchKernelGGL(k_gemm1, dim3(512), dim3(512), 0, stream, te, tpb, tpwb, comb);
  hipLaunchKernelGGL(k_attn, dim3(16384), dim3(256), 0, stream, comb, U, R, S, wabc, cabc, urs);
  hipLaunchKernelGGL(k_gru, dim3(32), dim3(256), 0, stream, whh, bhh, gx, urs, comb);
  hipLaunchKernelGGL(k_mlp, dim3(512), dim3(512), 0, stream, comb, w1b, b1, w2b, b2, out);
}